// Round 11
// baseline (3083.826 us; speedup 1.0000x reference)
//
#include <hip/hip_runtime.h>

// ---------------------------------------------------------------------------
// MambaEncoder on MI355X — round 15: scan VGPR diet -> 4 waves/SIMD.
//  * r14 lesson: scan residency was capped by VGPR=160 (3 waves/SIMD, 3
//    blocks/CU); doubling the grid (NSEG 20) couldn't help. Fix the cap:
//    __launch_bounds__(256,4), generic-path ac[16] -> LDS, POW path walks
//    B/C in 4x4 chunks with incremental eq *= q^4 (no e[16]/bs[16]/cs[16]).
//  * NSEG=20 segmented scan, bf16 scratch, dtsum-E, fast softplus/gelu,
//    split-K xproj: unchanged from r14.
// Dims: NL=8, DM=512, DI=1024, DS=16, DC=4, DR=32, B=8, L=800.
// ---------------------------------------------------------------------------

typedef unsigned short u16;
typedef unsigned long long u64;
typedef short s16x8 __attribute__((ext_vector_type(8)));   // 8 bf16 (4 VGPR)
typedef float f32x4 __attribute__((ext_vector_type(4)));   // 4 fp32 acc

#define NSEG 20
#define SEGLEN 40

__device__ __forceinline__ float b2f(u16 u) {
    return __uint_as_float(((unsigned)u) << 16);
}
__device__ __forceinline__ u16 f2b(float f) {
    unsigned u = __float_as_uint(f);
    return (u16)((u + 0x7fffu + ((u >> 16) & 1u)) >> 16);   // RNE
}
__device__ __forceinline__ float ldw(const void* p, size_t i, int bf) {
    return bf ? b2f(((const u16*)p)[i]) : ((const float*)p)[i];
}
__device__ __forceinline__ float4 ldw4(const void* p, size_t i, int bf) {
    if (bf) {
        ushort4 v = *(const ushort4*)((const u16*)p + i);
        return make_float4(b2f(v.x), b2f(v.y), b2f(v.z), b2f(v.w));
    }
    return *(const float4*)((const float*)p + i);
}

// Per-wave dtype sniff of patch_w (values ~N(0,0.02)): bf16 storage -> all 64
// sampled u16s have sane exponents; fp32 storage -> only high halves (~36/64).
__device__ __forceinline__ int detect_bf(const void* w) {
    const u16* p = (const u16*)w;
    unsigned e = (p[threadIdx.x & 63] >> 7) & 0xFFu;
    u64 m = __ballot((e >= 0x60u) && (e <= 0x7Fu));
    return __popcll(m) >= 50 ? 1 : 0;
}

#if __has_builtin(__builtin_amdgcn_exp2f)
#define EXP2F(x) __builtin_amdgcn_exp2f(x)
#else
#define EXP2F(x) __expf((x) * 0.69314718055994531f)
#endif

// EPI: 0 none(no bias), 1 +bias, 2 +bias softplus, 3 +bias gelu
template<int EPI>
__device__ __forceinline__ float epi_act(float x) {
    if (EPI == 2) {
        // softplus: stable both tails, hw exp/log only (~10 VALU ops)
        float t = __expf(-fabsf(x));
        return fmaxf(x, 0.f) + __logf(1.f + t);
    }
    if (EPI == 3) {
        // tanh-form gelu; |err| < 3e-4 << bf16 ulp of the consuming store
        float y = 0.7978845608f * fmaf(0.044715f * x, x * x, x);
        float e = __expf(fminf(2.f * y, 80.f));       // guard overflow
        float th = (e - 1.f) / (e + 1.f);
        return 0.5f * x * (1.f + th);
    }
    return x;
}

// ---------------- one-time weight transpose-convert: W[K][N] -> WT[N][K] bf16
__global__ __launch_bounds__(256) void transp_cvt(
    const void* __restrict__ src, u16* __restrict__ dst, int K, int N,
    const void* __restrict__ sniff)
{
    const int bf = detect_bf(sniff);
    __shared__ u16 tile[32][33];
    const int n0 = blockIdx.x * 32, k0 = blockIdx.y * 32;
    const size_t loff = (size_t)blockIdx.z * K * N;
    const int tx = threadIdx.x, ty = threadIdx.y;
    #pragma unroll
    for (int r = 0; r < 4; r++) {
        int ky = ty + r * 8;
        tile[ky][tx] = f2b(ldw(src, loff + (size_t)(k0 + ky) * N + n0 + tx, bf));
    }
    __syncthreads();
    #pragma unroll
    for (int r = 0; r < 4; r++) {
        int ny = ty + r * 8;
        dst[loff + (size_t)(n0 + ny) * K + k0 + tx] = tile[tx][ny];
    }
}

// ---------------- bf16 MFMA GEMM: C = act(A @ W (+bias)) -------------------
template<int EPI, bool OUTF, bool OUTB>
__global__ __launch_bounds__(256) void gemm_mfma(
    const u16* __restrict__ A, const u16* __restrict__ WT, size_t woff,
    const void* __restrict__ bias, size_t soff,
    float* __restrict__ Cf, u16* __restrict__ Cb,
    int M, int N, int K, const void* __restrict__ sniff)
{
    const int bf = detect_bf(sniff);
    __shared__ __align__(16) u16 As[128 * 32];
    __shared__ __align__(16) u16 Bs[128 * 32];
    const int tid = threadIdx.x;
    const int bm = blockIdx.y * 128, bn = blockIdx.x * 128;
    const int w = tid >> 6, lane = tid & 63;
    const int wm = (w >> 1) * 64, wn = (w & 1) * 64;
    const int lrow = lane & 15, q = lane >> 4;
    const u16* Wp = WT + woff;

    f32x4 acc[4][4];
    const f32x4 z4 = {0.f, 0.f, 0.f, 0.f};
    #pragma unroll
    for (int i = 0; i < 4; i++)
        #pragma unroll
        for (int j = 0; j < 4; j++) acc[i][j] = z4;

    for (int k0 = 0; k0 < K; k0 += 32) {
        if (k0) __syncthreads();
        #pragma unroll
        for (int c = 0; c < 2; c++) {
            int jj = tid + c * 256;            // 512 chunks of 16B per tile
            int r = jj >> 2, kc = jj & 3;
            int kg = kc ^ ((r >> 1) & 3);      // swizzled source chunk
            int ra = bm + r; if (ra >= M) ra = M - 1;
            *(s16x8*)(As + r * 32 + kc * 8) =
                *(const s16x8*)(A + (size_t)ra * K + k0 + kg * 8);
            *(s16x8*)(Bs + r * 32 + kc * 8) =
                *(const s16x8*)(Wp + (size_t)(bn + r) * K + k0 + kg * 8);
        }
        __syncthreads();
        s16x8 af[4], bfr[4];
        #pragma unroll
        for (int mt = 0; mt < 4; mt++) {
            int m_ = wm + mt * 16 + lrow;
            af[mt] = *(const s16x8*)(As + m_ * 32 + ((q ^ ((m_ >> 1) & 3)) << 3));
        }
        #pragma unroll
        for (int nt = 0; nt < 4; nt++) {
            int n_ = wn + nt * 16 + lrow;
            bfr[nt] = *(const s16x8*)(Bs + n_ * 32 + ((q ^ ((n_ >> 1) & 3)) << 3));
        }
        #pragma unroll
        for (int mt = 0; mt < 4; mt++)
            #pragma unroll
            for (int nt = 0; nt < 4; nt++)
                acc[mt][nt] = __builtin_amdgcn_mfma_f32_16x16x32_bf16(
                    af[mt], bfr[nt], acc[mt][nt], 0, 0, 0);
    }

    float bv[4] = {0.f, 0.f, 0.f, 0.f};
    if (EPI >= 1) {
        #pragma unroll
        for (int nt = 0; nt < 4; nt++)
            bv[nt] = ldw(bias, soff + (size_t)(bn + wn + nt * 16 + lrow), bf);
    }
    #pragma unroll
    for (int mt = 0; mt < 4; mt++) {
        #pragma unroll
        for (int nt = 0; nt < 4; nt++) {
            int n = bn + wn + nt * 16 + lrow;
            #pragma unroll
            for (int reg = 0; reg < 4; reg++) {
                int m = bm + wm + mt * 16 + q * 4 + reg;
                if (m < M) {
                    float v = epi_act<EPI>(acc[mt][nt][reg] + bv[nt]);
                    if (OUTF) Cf[(size_t)m * N + n] = v;
                    if (OUTB) Cb[(size_t)m * N + n] = f2b(v);
                }
            }
        }
    }
}

// ---------------- fp32 GEMM body (kept for dt; A fp32 internal) ------------
template<int EPI>
__device__ __forceinline__ void gemm_body(
    const float* __restrict__ A,
    const void* __restrict__ Bw, size_t boff,
    const void* __restrict__ bias, size_t soff,
    float* __restrict__ C, int N, int K, int lda, int ldb, int ldc, int bf)
{
    __shared__ float As[16][68];
    __shared__ float Bs[16][68];
    const int tid = threadIdx.x;
    const int bm = blockIdx.y * 64;
    const int bn = blockIdx.x * 64;
    const int arow = tid >> 2, acol = (tid & 3) << 2;
    const int brow = tid >> 4, bcol = (tid & 15) << 2;
    const int ty = tid >> 4, tx = tid & 15;
    float acc[4][4] = {};

    const float* aptr = A + (size_t)(bm + arow) * lda + acol;
    const size_t bidx0 = boff + (size_t)brow * ldb + bn + bcol;

    for (int k0 = 0; k0 < K; k0 += 16) {
        float4 av = *(const float4*)(aptr + k0);
        float4 bvv = ldw4(Bw, bidx0 + (size_t)k0 * ldb, bf);
        As[acol + 0][arow] = av.x;
        As[acol + 1][arow] = av.y;
        As[acol + 2][arow] = av.z;
        As[acol + 3][arow] = av.w;
        Bs[brow][bcol + 0] = bvv.x;
        Bs[brow][bcol + 1] = bvv.y;
        Bs[brow][bcol + 2] = bvv.z;
        Bs[brow][bcol + 3] = bvv.w;
        __syncthreads();
        #pragma unroll
        for (int kk = 0; kk < 16; kk++) {
            float4 a4 = *(const float4*)&As[kk][ty << 2];
            float4 b4 = *(const float4*)&Bs[kk][tx << 2];
            float ar[4] = {a4.x, a4.y, a4.z, a4.w};
            float br[4] = {b4.x, b4.y, b4.z, b4.w};
            #pragma unroll
            for (int i = 0; i < 4; i++)
                #pragma unroll
                for (int j = 0; j < 4; j++)
                    acc[i][j] = fmaf(ar[i], br[j], acc[i][j]);
        }
        __syncthreads();
    }

    float bv4[4] = {0.f, 0.f, 0.f, 0.f};
    if (EPI >= 1) {
        float4 bb = ldw4(bias, soff + (size_t)(bn + (tx << 2)), bf);
        bv4[0] = bb.x; bv4[1] = bb.y; bv4[2] = bb.z; bv4[3] = bb.w;
    }
    #pragma unroll
    for (int i = 0; i < 4; i++) {
        float4 o;
        o.x = epi_act<EPI>(acc[i][0] + bv4[0]);
        o.y = epi_act<EPI>(acc[i][1] + bv4[1]);
        o.z = epi_act<EPI>(acc[i][2] + bv4[2]);
        o.w = epi_act<EPI>(acc[i][3] + bv4[3]);
        *(float4*)(C + (size_t)(bm + (ty << 2) + i) * ldc + bn + (tx << 2)) = o;
    }
}

template<int EPI>
__global__ __launch_bounds__(256) void gemm_dual(
    const float* __restrict__ A0, const float* __restrict__ A1,
    const void* __restrict__ Bw0, size_t boff0,
    const void* __restrict__ Bw1, size_t boff1,
    const void* __restrict__ bias0, size_t sof0,
    const void* __restrict__ bias1, size_t sof1,
    float* __restrict__ C0, float* __restrict__ C1,
    int N, int K, int lda, int ldb, int ldc,
    const void* __restrict__ sniff)
{
    const int bf = detect_bf(sniff);
    if (blockIdx.z == 0)
        gemm_body<EPI>(A0, Bw0, boff0, bias0, sof0, C0, N, K, lda, ldb, ldc, bf);
    else
        gemm_body<EPI>(A1, Bw1, boff1, bias1, sof1, C1, N, K, lda, ldb, ldc, bf);
}

// ---------------- xproj split-K: (Mc x 1024)@(1024 x 64), K-chunk 128 ------
// grid (8, Mc/64, 2); partials P[(kc*2+dir)][Mc][64] (DTF arena).
__global__ __launch_bounds__(256) void xproj_splitk(
    const float* __restrict__ A0, const float* __restrict__ A1,
    const void* __restrict__ Bw0, size_t boff0,
    const void* __restrict__ Bw1, size_t boff1,
    float* __restrict__ P, int Mc, const void* __restrict__ sniff)
{
    const int bf = detect_bf(sniff);
    const int dir = blockIdx.z;
    const float* A = dir ? A1 : A0;
    const void* Bw = dir ? Bw1 : Bw0;
    const size_t boff = dir ? boff1 : boff0;

    __shared__ float As[16][68];
    __shared__ float Bs[16][68];
    const int tid = threadIdx.x;
    const int bm = blockIdx.y * 64;
    const int kbase = blockIdx.x * 128;
    const int arow = tid >> 2, acol = (tid & 3) << 2;
    const int brow = tid >> 4, bcol = (tid & 15) << 2;
    const int ty = tid >> 4, tx = tid & 15;
    float acc[4][4] = {};

    const float* aptr = A + (size_t)(bm + arow) * 1024 + kbase + acol;
    const size_t bidx0 = boff + (size_t)(kbase + brow) * 64 + bcol;

    for (int k0 = 0; k0 < 128; k0 += 16) {
        float4 av = *(const float4*)(aptr + k0);
        float4 bvv = ldw4(Bw, bidx0 + (size_t)k0 * 64, bf);
        As[acol + 0][arow] = av.x;
        As[acol + 1][arow] = av.y;
        As[acol + 2][arow] = av.z;
        As[acol + 3][arow] = av.w;
        Bs[brow][bcol + 0] = bvv.x;
        Bs[brow][bcol + 1] = bvv.y;
        Bs[brow][bcol + 2] = bvv.z;
        Bs[brow][bcol + 3] = bvv.w;
        __syncthreads();
        #pragma unroll
        for (int kk = 0; kk < 16; kk++) {
            float4 a4 = *(const float4*)&As[kk][ty << 2];
            float4 b4 = *(const float4*)&Bs[kk][tx << 2];
            float ar[4] = {a4.x, a4.y, a4.z, a4.w};
            float br[4] = {b4.x, b4.y, b4.z, b4.w};
            #pragma unroll
            for (int i = 0; i < 4; i++)
                #pragma unroll
                for (int j = 0; j < 4; j++)
                    acc[i][j] = fmaf(ar[i], br[j], acc[i][j]);
        }
        __syncthreads();
    }

    float* out = P + ((size_t)(blockIdx.x * 2 + dir) * Mc + bm) * 64;
    #pragma unroll
    for (int i = 0; i < 4; i++) {
        float4 o = {acc[i][0], acc[i][1], acc[i][2], acc[i][3]};
        *(float4*)(out + (size_t)((ty << 2) + i) * 64 + (tx << 2)) = o;
    }
}

// reduce 8 split-K partials -> PRF/PRB.  grid (Mc/16, 2): dir = blockIdx.y.
__global__ __launch_bounds__(256) void xproj_reduce(
    const float* __restrict__ P, float* __restrict__ o0,
    float* __restrict__ o1, unsigned Md)
{
    const int dir = blockIdx.y;
    unsigned i = (blockIdx.x * 256 + threadIdx.x) * 4;
    const float* p = P + (size_t)dir * Md + i;
    float4 a = *(const float4*)p;
    #pragma unroll
    for (int kc = 1; kc < 8; kc++) {
        float4 bq = *(const float4*)(p + (size_t)kc * 2 * Md);
        a.x += bq.x; a.y += bq.y; a.z += bq.z; a.w += bq.w;
    }
    *(float4*)((dir ? o1 : o0) + i) = a;
}

// ---------------- patch gather (im2col) -> bf16 A ---------------------------
__global__ __launch_bounds__(256) void im2col_patch(
    const void* __restrict__ x, size_t x0, u16* __restrict__ Pb,
    const void* __restrict__ sniff)
{
    const int bf = detect_bf(sniff);
    int idx = blockIdx.x * 256 + threadIdx.x;
    int p2 = idx & 15; int r = idx >> 4;
    int p1 = r & 15;  r >>= 4;
    int w = r % 10;   r /= 10;
    int h = r % 10;   r /= 10;
    int f = r & 7;    int b = r >> 3;
    int token = f * 100 + h * 10 + w;
    size_t xb = x0 + ((size_t)(b * 32 + f * 4) * 160 + h * 16 + p1) * 160
                   + (w * 16 + p2);
    ushort4 o;
    o.x = f2b(ldw(x, xb,         bf));
    o.y = f2b(ldw(x, xb + 25600, bf));
    o.z = f2b(ldw(x, xb + 51200, bf));
    o.w = f2b(ldw(x, xb + 76800, bf));
    *(ushort4*)(Pb + (size_t)(b * 800 + token) * 1024 + ((p1 * 16 + p2) << 2)) = o;
}

// ---------------- dual depthwise conv + SiLU (fp32) ------------------------
__global__ __launch_bounds__(256) void conv_dual(
    const float* __restrict__ xm,
    const void* __restrict__ cwF, size_t wFo,
    const void* __restrict__ cbF, size_t bFo,
    const void* __restrict__ cwB, size_t wBo,
    const void* __restrict__ cbB, size_t bBo,
    float* __restrict__ xcf, float* __restrict__ xcb,
    const void* __restrict__ sniff)
{
    const int bf = detect_bf(sniff);
    int idx = blockIdx.x * 256 + threadIdx.x;
    int d = idx & 1023;
    int bt = idx >> 10;
    int t = bt % 800, b = bt / 800;
    const float* base = xm + (size_t)b * 800 * 2048 + d;
    float v[7];
    #pragma unroll
    for (int j = 0; j < 7; j++) {
        int tt = t + j - 3;
        v[j] = (tt >= 0 && tt < 800) ? base[(size_t)tt * 2048] : 0.f;
    }
    float4 wf = ldw4(cwF, wFo + (size_t)d * 4, bf);
    float4 wb = ldw4(cwB, wBo + (size_t)d * 4, bf);
    float f = ldw(cbF, bFo + d, bf) + wf.x * v[0] + wf.y * v[1]
                                    + wf.z * v[2] + wf.w * v[3];
    float g = ldw(cbB, bBo + d, bf) + wb.x * v[6] + wb.y * v[5]
                                    + wb.z * v[4] + wb.w * v[3];
    xcf[(size_t)bt * 1024 + d] = f / (1.f + __expf(-f));
    xcb[(size_t)bt * 1024 + d] = g / (1.f + __expf(-g));
}

// ---------------- segmented selective scan (round 15: VGPR diet) -----------
// scratch = u16 planes in the dead XZ x-half: u16 index i ->
// XZ_u16[(i>>11)*4096 + (i&2047)] (row = 2048 u16 of x-half, stride 4096).
__device__ __forceinline__ u16& scrh(u16* s, unsigned i) {
    return s[(size_t)(i >> 11) * 4096 + (i & 2047)];
}

// q^(1..16) with 15 muls, depth <= 4 (epilogue only)
__device__ __forceinline__ void pow16(float q, float* e) {
    float q2 = q * q, q4 = q2 * q2, q8 = q4 * q4;
    e[0] = q;        e[1] = q2;       e[2] = q2 * q;   e[3] = q4;
    e[4] = q4 * q;   e[5] = q4 * q2;  e[6] = e[5] * q; e[7] = q8;
    e[8] = q8 * q;   e[9] = q8 * q2;  e[10] = e[9] * q; e[11] = q8 * q4;
    e[12] = e[11] * q; e[13] = e[11] * q2; e[14] = e[13] * q; e[15] = q8 * q8;
}

// PASS=1: per-segment transfer (E via exp2(ac*sum dt), h_end from 0) -> scratch.
// PASS=3: full scan with h_in from scratch; y = c + u*D in place over u.
// Hot loop walks B/C in 4x4 chunks; POW path uses eq *= q^4 recurrence.
// Generic path reads per-thread ac from LDS (acl) — cold, correctness-only.
template<int DIR, int PASS, bool POW>
__device__ __forceinline__ void scan_seg_body(
    const float* u, const float* dt, const float* __restrict__ pr,
    const void* __restrict__ Al, size_t ao,
    const void* __restrict__ Dp, size_t dofs,
    float* y, u16* scr, unsigned NSd, int b, int seg, int bf,
    float* lds, float* acl)
{
    const int tid = threadIdx.x;
    const int d = blockIdx.x * 256 + tid;
    const long rb = (long)b * 800;
    constexpr int S = DIR ? -1 : 1;
    const int t0 = DIR ? 799 - seg * SEGLEN : seg * SEGLEN;

    // stage this segment's B/C rows into LDS: lds[tau][32] (tau in [0,40))
    for (int i = tid; i < SEGLEN * 8; i += 256) {
        int tr = i >> 3, c4 = (i & 7) * 4;
        long tt = (long)t0 + (long)(S * tr);
        *(float4*)&lds[tr * 32 + c4] =
            *(const float4*)&pr[(rb + tt) * 64 + 32 + c4];
    }

    // per-lane constants: POW keeps only ac0; generic parks ac[16] in LDS
    float ac0;
    if (POW) {
        ac0 = -__expf(ldw(Al, ao + (size_t)d * 16, bf)) * 1.44269504f;
    } else {
        #pragma unroll
        for (int n = 0; n < 16; n++)
            acl[tid * 16 + n] =
                -__expf(ldw(Al, ao + (size_t)d * 16 + n, bf)) * 1.44269504f;
        ac0 = acl[tid * 16];
    }
    __syncthreads();
    const float Dv = (PASS == 3) ? ldw(Dp, dofs + d, bf) : 0.f;

    const unsigned sidx = ((unsigned)((b * 2 + DIR) * NSEG + seg) << 10) + d;
    float h[16];
    if (PASS == 3) {
        #pragma unroll
        for (int n = 0; n < 16; n++) h[n] = b2f(scrh(scr, (16 + n) * NSd + sidx));
    } else {
        #pragma unroll
        for (int n = 0; n < 16; n++) h[n] = 0.f;
    }
    float dtsum = 0.f;

    const float* pdt = dt + (rb + t0) * 1024 + d;
    const float* pu  = u  + (rb + t0) * 1024 + d;
    float*       py  = y  + (rb + t0) * 1024 + d;

    float dA[8], uA[8], dB[8], uB_[8];
    #pragma unroll
    for (int j = 0; j < 8; j++) { dA[j] = pdt[S * j * 1024]; uA[j] = pu[S * j * 1024]; }
    pdt += S * 8192; pu += S * 8192;

    for (int it = 0; it < SEGLEN / 8; it++) {
        // prefetch next 8 steps (last iteration over-reads 8 rows: discarded,
        // and the addresses stay inside adjacent workspace buffers)
        #pragma unroll
        for (int j = 0; j < 8; j++) { dB[j] = pdt[S * j * 1024]; uB_[j] = pu[S * j * 1024]; }
        pdt += S * 8192; pu += S * 8192;

        #pragma unroll
        for (int j = 0; j < 8; j++) {
            const float dtv = dA[j], uv = uA[j];
            const float du = dtv * uv;
            if (PASS == 1) dtsum += dtv;
            const float* bcp = lds + (it * 8 + j) * 32;
            float s0 = 0.f, s1 = 0.f;
            if (POW) {
                float qq = EXP2F(dtv * ac0);
                float q2 = qq * qq;
                float e0 = qq, e1 = q2, e2 = q2 * qq, e3 = q2 * q2;
                const float q4 = e3;
                #pragma unroll
                for (int c = 0; c < 4; c++) {
                    float4 bq = *(const float4*)&bcp[c * 4];
                    h[c*4+0] = e0 * h[c*4+0] + du * bq.x;
                    h[c*4+1] = e1 * h[c*4+1] + du * bq.y;
                    h[c*4+2] = e2 * h[c*4+2] + du * bq.z;
                    h[c*4+3] = e3 * h[c*4+3] + du * bq.w;
                    if (PASS == 3) {
                        float4 cq = *(const float4*)&bcp[16 + c * 4];
                        s0 = fmaf(h[c*4+0], cq.x, fmaf(h[c*4+1], cq.y, s0));
                        s1 = fmaf(h[c*4+2], cq.z, fmaf(h[c*4+3], cq.w, s1));
                    }
                    if (c < 3) { e0 *= q4; e1 *= q4; e2 *= q4; e3 *= q4; }
                }
            } else {
                #pragma unroll
                for (int c = 0; c < 4; c++) {
                    float4 bq = *(const float4*)&bcp[c * 4];
                    float e0 = EXP2F(dtv * acl[tid * 16 + c*4+0]);
                    float e1 = EXP2F(dtv * acl[tid * 16 + c*4+1]);
                    float e2 = EXP2F(dtv * acl[tid * 16 + c*4+2]);
                    float e3 = EXP2F(dtv * acl[tid * 16 + c*4+3]);
                    h[c*4+0] = e0 * h[c*4+0] + du * bq.x;
                    h[c*4+1] = e1 * h[c*4+1] + du * bq.y;
                    h[c*4+2] = e2 * h[c*4+2] + du * bq.z;
                    h[c*4+3] = e3 * h[c*4+3] + du * bq.w;
                    if (PASS == 3) {
                        float4 cq = *(const float4*)&bcp[16 + c * 4];
                        s0 = fmaf(h[c*4+0], cq.x, fmaf(h[c*4+1], cq.y, s0));
                        s1 = fmaf(h[c*4+2], cq.z, fmaf(h[c*4+3], cq.w, s1));
                    }
                }
            }
            if (PASS == 3) py[S * j * 1024] = fmaf(uv, Dv, s0 + s1);
        }
        if (PASS == 3) py += S * 8192;
        #pragma unroll
        for (int j = 0; j < 8; j++) { dA[j] = dB[j]; uA[j] = uB_[j]; }
    }

    if (PASS == 1) {
        float E[16];
        if (POW) {
            pow16(EXP2F(dtsum * ac0), E);
        } else {
            #pragma unroll
            for (int n = 0; n < 16; n++) E[n] = EXP2F(dtsum * acl[tid * 16 + n]);
        }
        #pragma unroll
        for (int n = 0; n < 16; n++) {
            scrh(scr, n * NSd + sidx)        = f2b(E[n]);
            scrh(scr, (16 + n) * NSd + sidx) = f2b(h[n]);
        }
    }
}

template<int PASS>
__global__ __launch_bounds__(256, 4) void ssm_seg(
    const float* uF, const float* dtF, const float* __restrict__ pF,
    const float* uB, const float* dtB, const float* __restrict__ pB,
    const void* __restrict__ AlF, const void* __restrict__ AlB, size_t ao,
    const void* __restrict__ DF,  const void* __restrict__ DB,  size_t dofs,
    float* yF, float* yB, u16* scr, unsigned NSd,
    const void* __restrict__ sniff)
{
    __shared__ float lds[SEGLEN * 32];
    __shared__ float acl[256 * 16];
    const int bf = detect_bf(sniff);
    const int b = blockIdx.y;
    const int z = blockIdx.z;
    const int dir = z >= NSEG ? 1 : 0;
    const int seg = dir ? z - NSEG : z;
    const int d = blockIdx.x * 256 + threadIdx.x;

    // detect A-structure: A_log[d][n] == A_log[d][0] + log(n+1)  (per wave)
    const void* Al = dir ? AlB : AlF;
    float m0 = __expf(ldw(Al, ao + (size_t)d * 16 + 0, bf));
    bool okb = true;
    #pragma unroll
    for (int n = 1; n < 16; n++) {
        float mn = __expf(ldw(Al, ao + (size_t)d * 16 + n, bf));
        okb &= fabsf(mn - (n + 1) * m0) <= 1e-3f * (n + 1) * m0;
    }
    const bool ok = __all(okb) != 0;

    if (dir == 0) {
        if (ok) scan_seg_body<0, PASS, true >(uF, dtF, pF, AlF, ao, DF, dofs,
                                              yF, scr, NSd, b, seg, bf, lds, acl);
        else    scan_seg_body<0, PASS, false>(uF, dtF, pF, AlF, ao, DF, dofs,
                                              yF, scr, NSd, b, seg, bf, lds, acl);
    } else {
        if (ok) scan_seg_body<1, PASS, true >(uB, dtB, pB, AlB, ao, DB, dofs,
                                              yB, scr, NSd, b, seg, bf, lds, acl);
        else    scan_seg_body<1, PASS, false>(uB, dtB, pB, AlB, ao, DB, dofs,
                                              yB, scr, NSd, b, seg, bf, lds, acl);
    }
}

// pass 2: sequential cross-segment combine; rewrites h_end slot with h_in.
// h carried in fp32 internally; scratch slots are bf16.
__global__ __launch_bounds__(256) void ssm_comb(u16* scr, unsigned NSd)
{
    int idx = blockIdx.x * 256 + threadIdx.x;   // (bdir*16 + n)*1024 + d
    int d = idx & 1023;
    int n = (idx >> 10) & 15;
    int bdir = idx >> 14;
    float h = 0.f;
    for (int s = 0; s < NSEG; s++) {
        unsigned sidx = ((unsigned)(bdir * NSEG + s) << 10) + d;
        float Ev = b2f(scrh(scr, n * NSd + sidx));
        float He = b2f(scrh(scr, (16 + n) * NSd + sidx));
        scrh(scr, (16 + n) * NSd + sidx) = f2b(h);
        h = Ev * h + He;
    }
}

// ---------------- (yF + yB) * silu(z) -> bf16 (out_proj A) -----------------
__global__ __launch_bounds__(256) void addcvt(
    const float* __restrict__ a, const float* __restrict__ b,
    const float* __restrict__ z, u16* __restrict__ o)
{
    int i = (blockIdx.x * 256 + threadIdx.x) * 4;
    int t = i >> 10, d = i & 1023;
    float4 va = *(const float4*)(a + i);
    float4 vb = *(const float4*)(b + i);
    float4 vz = *(const float4*)(z + (size_t)t * 2048 + 1024 + d);
    float s0 = vz.x / (1.f + __expf(-vz.x));
    float s1 = vz.y / (1.f + __expf(-vz.y));
    float s2 = vz.z / (1.f + __expf(-vz.z));
    float s3 = vz.w / (1.f + __expf(-vz.w));
    ushort4 r;
    r.x = f2b((va.x + vb.x) * s0); r.y = f2b((va.y + vb.y) * s1);
    r.z = f2b((va.z + vb.z) * s2); r.w = f2b((va.w + vb.w) * s3);
    *(ushort4*)(o + i) = r;
}

// ---------------- LayerNorm + residual -> XT fp32 + XTb bf16 (+fp32 out) ---
__global__ __launch_bounds__(256) void ln_residual(
    const float* __restrict__ Y, const void* __restrict__ g, size_t go,
    const void* __restrict__ bb, size_t bo,
    float* __restrict__ XT, u16* __restrict__ XTb, float* __restrict__ out,
    const void* __restrict__ sniff)
{
    const int bf = detect_bf(sniff);
    int wv = threadIdx.x >> 6, lane = threadIdx.x & 63;
    int token = blockIdx.x * 4 + wv;
    const float* y = Y + (size_t)token * 512;
    float v[8], s = 0.f, s2 = 0.f;
    #pragma unroll
    for (int j = 0; j < 8; j++) {
        v[j] = y[lane + j * 64];
        s += v[j]; s2 += v[j] * v[j];
    }
    #pragma unroll
    for (int off = 32; off >= 1; off >>= 1) {
        s  += __shfl_xor(s,  off, 64);
        s2 += __shfl_xor(s2, off, 64);
    }
    float mean = s * (1.f / 512.f);
    float var  = s2 * (1.f / 512.f) - mean * mean;
    float rs = rsqrtf(var + 1e-5f);
    float* xt = XT + (size_t)token * 512;
    #pragma unroll
    for (int j = 0; j < 8; j++) {
        int c = lane + j * 64;
        float val = (v[j] - mean) * rs * ldw(g, go + c, bf)
                  + ldw(bb, bo + c, bf) + xt[c];
        xt[c] = val;
        XTb[(size_t)token * 512 + c] = f2b(val);
        if (out) out[(size_t)token * 512 + c] = val;
    }
}

// ---------------------------------------------------------------------------
extern "C" void kernel_launch(void* const* d_in, const int* in_sizes, int n_in,
                              void* d_out, int out_size, void* d_ws, size_t ws_size,
                              hipStream_t stream)
{
    (void)in_sizes; (void)n_in; (void)out_size;
    const void* X      = d_in[0];
    const void* patchW = d_in[1];
    const void* patchB = d_in[2];
    const void* inW    = d_in[3];
    const void* convW  = d_in[4];
    const void* convBi = d_in[5];
    const void* xprojW = d_in[6];
    const void* dtW    = d_in[7];
    const void* dtBias = d_in[8];
    const void* Alog   = d_in[9];
    const void* Dsk    = d_in[10];
    const void* convWb = d_in[11];
    const void* convBb = d_in[12];
    const void* xprojWb= d_in[13];
    const void* dtWb   = d_in[14];
    const void* dtBiasb= d_in[15];
    const void* Alogb  = d_in[16];
    const void* Dskb   = d_in[17];
    const void* outW   = d_in[18];
    const void* ln1g   = d_in[19];
    const void* ln1b   = d_in[20];
    const void* fc1W   = d_in[21];
    const void* fc1B   = d_in[22];
    const void* fc2W   = d_in[23];
    const void* fc2B   = d_in[24];
    const void* ln2g   = d_in[25];
    const void* ln2b   = d_in[26];
    const void* SN     = patchW;            // dtype sniff target

    // bf16 weight arena (u16 offsets)
    const size_t IN_OFF  = 524288;          // after patchWT
    const size_t OUT_OFF = 8912896;
    const size_t FC1_OFF = 13107200;
    const size_t FC2_OFF = 17301504;
    const size_t WB_FLOATS = 10747904;      // 21495808 u16 / 2

    // chunking: bytes = (WB + Mc*8064 + pad)*4
    int nc = 1;
    auto need = [&](int Mc) {
        return (WB_FLOATS + (size_t)Mc * 8064 + 16384) * 4;
    };
    if (need(6400) > ws_size) nc = 2;
    if (need(3200) > ws_size) nc = 4;
    const int bc = 8 / nc;
    const int Mc = bc * 800;
    const int GY = Mc / 64;                 // fp32-GEMM grid
    const int GYM = (Mc + 127) / 128;       // MFMA grid
    const unsigned NSd = (unsigned)bc * 2 * NSEG * 1024;   // scratch streams

    u16* WB = (u16*)d_ws;
    float* cur = (float*)d_ws + WB_FLOATS;
    float* XT  = cur;              cur += (size_t)Mc * 512;
    u16*  XTb  = (u16*)cur;        cur += (size_t)Mc * 256;
    float* XZ  = cur;              cur += (size_t)Mc * 2048;
    float* XCF = cur;              cur += (size_t)Mc * 1024;
    float* XCB = cur;              cur += (size_t)Mc * 1024;
    float* PRF = cur;              cur += (size_t)Mc * 64;
    float* PRB = cur;              cur += (size_t)Mc * 64;
    float* DTF = cur;              cur += (size_t)Mc * 1024;
    float* DTB = cur;              cur += (size_t)Mc * 1024;
    u16*  M1b  = (u16*)cur;        cur += (size_t)Mc * 512;
    u16*  YSb  = (u16*)cur;        cur += (size_t)Mc * 512;
    u16*  PATCHb = (u16*)XCF;               // alias (dead before conv)
    float* YO  = XZ;                        // alias (XZ dead post-scan)
    float* M2  = XZ + (size_t)Mc * 512;     // alias, disjoint from YO

    // ---- one-time weight transpose-convert to bf16 [N][K] -----------------
    transp_cvt<<<dim3(16, 32, 1), dim3(32, 8), 0, stream>>>(patchW, WB, 1024, 512, SN);
    transp_cvt<<<dim3(64, 16, 8), dim3(32, 8), 0, stream>>>(inW,  WB + IN_OFF, 512, 2048, SN);
    transp_cvt<<<dim3(16, 32, 8), dim3(32, 8), 0, stream>>>(outW, WB + OUT_OFF, 1024, 512, SN);
    transp_cvt<<<dim3(32, 16, 8), dim3(32, 8), 0, stream>>>(fc1W, WB + FC1_OFF, 512, 1024, SN);
    transp_cvt<<<dim3(16, 32, 8), dim3(32, 8), 0, stream>>>(fc2W, WB + FC2_OFF, 1024, 512, SN);

    for (int c = 0; c < nc; c++) {
        const size_t x0 = (size_t)c * bc * 819200;

        im2col_patch<<<Mc, 256, 0, stream>>>(X, x0, PATCHb, SN);
        // patch embed: (Mc x 1024) @ (1024 x 512) + bias -> XT fp32 + XTb bf16
        gemm_mfma<1, true, true><<<dim3(4, GYM), 256, 0, stream>>>(
            PATCHb, WB, 0, patchB, 0, XT, XTb, Mc, 512, 1024, SN);

        for (int l = 0; l < 8; l++) {
            // in_proj: (Mc x 512) @ (512 x 2048) -> XZ fp32
            gemm_mfma<0, true, false><<<dim3(16, GYM), 256, 0, stream>>>(
                XTb, WB, IN_OFF + (size_t)l * 1048576, nullptr, 0,
                XZ, nullptr, Mc, 2048, 512, SN);
            // depthwise conv both dirs + SiLU
            conv_dual<<<Mc * 4, 256, 0, stream>>>(
                XZ, convW, (size_t)l * 4096, convBi, (size_t)l * 1024,
                convWb, (size_t)l * 4096, convBb, (size_t)l * 1024,
                XCF, XCB, SN);
            // x-proj both dirs, split-K 8 (fp32): partials in DTF arena
            xproj_splitk<<<dim3(8, GY, 2), 256, 0, stream>>>(
                XCF, XCB, xprojW, (size_t)l * 65536, xprojWb, (size_t)l * 65536,
                DTF, Mc, SN);
            xproj_reduce<<<dim3(Mc / 16, 2), 256, 0, stream>>>(
                DTF, PRF, PRB, (unsigned)Mc * 64);
            // dt both dirs (fp32): softplus((Mc x 32) @ (32 x 1024) + bias)
            gemm_dual<2><<<dim3(16, GY, 2), 256, 0, stream>>>(
                PRF, PRB, dtW, (size_t)l * 32768, dtWb, (size_t)l * 32768,
                dtBias, (size_t)l * 1024, dtBiasb, (size_t)l * 1024,
                DTF, DTB, 1024, 32, 64, 1024, 1024, SN);
            // segmented selective scan: pass1 (transfer), pass2 (combine),
            // pass3 (scan; in-place raw y = c + u*D over u). scratch = XZ x-half (bf16).
            ssm_seg<1><<<dim3(4, bc, 2 * NSEG), 256, 0, stream>>>(
                XCF, DTF, PRF, XCB, DTB, PRB,
                Alog, Alogb, (size_t)l * 16384,
                Dsk, Dskb, (size_t)l * 1024,
                XCF, XCB, (u16*)XZ, NSd, SN);
            ssm_comb<<<bc * 128, 256, 0, stream>>>((u16*)XZ, NSd);
            ssm_seg<3><<<dim3(4, bc, 2 * NSEG), 256, 0, stream>>>(
                XCF, DTF, PRF, XCB, DTB, PRB,
                Alog, Alogb, (size_t)l * 16384,
                Dsk, Dskb, (size_t)l * 1024,
                XCF, XCB, (u16*)XZ, NSd, SN);
            // (yF + yB) * silu(z) -> bf16
            addcvt<<<Mc, 256, 0, stream>>>(XCF, XCB, XZ, YSb);
            // out_proj: (Mc x 1024) @ (1024 x 512) -> YO fp32
            gemm_mfma<0, true, false><<<dim3(4, GYM), 256, 0, stream>>>(
                YSb, WB, OUT_OFF + (size_t)l * 524288, nullptr, 0,
                YO, nullptr, Mc, 512, 1024, SN);
            ln_residual<<<Mc / 4, 256, 0, stream>>>(
                YO, ln1g, (size_t)l * 512, ln1b, (size_t)l * 512,
                XT, XTb, nullptr, SN);
            // fc1: (Mc x 512) @ (512 x 1024) + bias, gelu -> M1b bf16
            gemm_mfma<3, false, true><<<dim3(8, GYM), 256, 0, stream>>>(
                XTb, WB, FC1_OFF + (size_t)l * 524288, fc1B, (size_t)l * 1024,
                nullptr, M1b, Mc, 1024, 512, SN);
            // fc2: (Mc x 1024) @ (1024 x 512) + bias -> M2 fp32
            gemm_mfma<1, true, false><<<dim3(4, GYM), 256, 0, stream>>>(
                M1b, WB, FC2_OFF + (size_t)l * 524288, fc2B, (size_t)l * 512,
                M2, nullptr, Mc, 512, 1024, SN);
            ln_residual<<<Mc / 4, 256, 0, stream>>>(
                M2, ln2g, (size_t)l * 512, ln2b, (size_t)l * 512,
                XT, XTb,
                (float*)d_out + (size_t)l * 3276800 + (size_t)c * Mc * 512, SN);
        }
    }
}

// Round 12
// 2888.833 us; speedup vs baseline: 1.0675x; 1.0675x over previous
//
#include <hip/hip_runtime.h>

// ---------------------------------------------------------------------------
// MambaEncoder on MI355X — round 16: bf16 activation storage for the scan.
//  * r15 lesson: scan passes are traffic-bound (197 MB @ 3.1 TB/s, VALU 42%).
//    Store dt (DTF/DTB) and u/y (XCF/XCB) as bf16: halves conv/xproj/dt-GEMM/
//    scan/addcvt traffic (~470 MB/layer). Arena layout unchanged (fp32-sized
//    allocations reinterpreted), so PATCHb / XZ-scratch / YO aliases hold.
//  * r15 scan structure kept: VGPR diet, 4 waves/SIMD, NSEG=20, bf16 scratch,
//    dtsum-E, 4x4 chunked hot loop, fast softplus/gelu, split-K xproj.
// Dims: NL=8, DM=512, DI=1024, DS=16, DC=4, DR=32, B=8, L=800.
// ---------------------------------------------------------------------------

typedef unsigned short u16;
typedef unsigned long long u64;
typedef short s16x8 __attribute__((ext_vector_type(8)));   // 8 bf16 (4 VGPR)
typedef float f32x4 __attribute__((ext_vector_type(4)));   // 4 fp32 acc

#define NSEG 20
#define SEGLEN 40

__device__ __forceinline__ float b2f(u16 u) {
    return __uint_as_float(((unsigned)u) << 16);
}
__device__ __forceinline__ u16 f2b(float f) {
    unsigned u = __float_as_uint(f);
    return (u16)((u + 0x7fffu + ((u >> 16) & 1u)) >> 16);   // RNE
}
__device__ __forceinline__ float ldw(const void* p, size_t i, int bf) {
    return bf ? b2f(((const u16*)p)[i]) : ((const float*)p)[i];
}
__device__ __forceinline__ float4 ldw4(const void* p, size_t i, int bf) {
    if (bf) {
        ushort4 v = *(const ushort4*)((const u16*)p + i);
        return make_float4(b2f(v.x), b2f(v.y), b2f(v.z), b2f(v.w));
    }
    return *(const float4*)((const float*)p + i);
}
__device__ __forceinline__ float4 ld4h(const u16* p, size_t i) {
    ushort4 v = *(const ushort4*)(p + i);
    return make_float4(b2f(v.x), b2f(v.y), b2f(v.z), b2f(v.w));
}

// Per-wave dtype sniff of patch_w (values ~N(0,0.02)): bf16 storage -> all 64
// sampled u16s have sane exponents; fp32 storage -> only high halves (~36/64).
__device__ __forceinline__ int detect_bf(const void* w) {
    const u16* p = (const u16*)w;
    unsigned e = (p[threadIdx.x & 63] >> 7) & 0xFFu;
    u64 m = __ballot((e >= 0x60u) && (e <= 0x7Fu));
    return __popcll(m) >= 50 ? 1 : 0;
}

#if __has_builtin(__builtin_amdgcn_exp2f)
#define EXP2F(x) __builtin_amdgcn_exp2f(x)
#else
#define EXP2F(x) __expf((x) * 0.69314718055994531f)
#endif

// EPI: 0 none(no bias), 1 +bias, 2 +bias softplus, 3 +bias gelu
template<int EPI>
__device__ __forceinline__ float epi_act(float x) {
    if (EPI == 2) {
        // softplus: stable both tails, hw exp/log only (~10 VALU ops)
        float t = __expf(-fabsf(x));
        return fmaxf(x, 0.f) + __logf(1.f + t);
    }
    if (EPI == 3) {
        // tanh-form gelu; |err| < 3e-4 << bf16 ulp of the consuming store
        float y = 0.7978845608f * fmaf(0.044715f * x, x * x, x);
        float e = __expf(fminf(2.f * y, 80.f));       // guard overflow
        float th = (e - 1.f) / (e + 1.f);
        return 0.5f * x * (1.f + th);
    }
    return x;
}

// ---------------- one-time weight transpose-convert: W[K][N] -> WT[N][K] bf16
__global__ __launch_bounds__(256) void transp_cvt(
    const void* __restrict__ src, u16* __restrict__ dst, int K, int N,
    const void* __restrict__ sniff)
{
    const int bf = detect_bf(sniff);
    __shared__ u16 tile[32][33];
    const int n0 = blockIdx.x * 32, k0 = blockIdx.y * 32;
    const size_t loff = (size_t)blockIdx.z * K * N;
    const int tx = threadIdx.x, ty = threadIdx.y;
    #pragma unroll
    for (int r = 0; r < 4; r++) {
        int ky = ty + r * 8;
        tile[ky][tx] = f2b(ldw(src, loff + (size_t)(k0 + ky) * N + n0 + tx, bf));
    }
    __syncthreads();
    #pragma unroll
    for (int r = 0; r < 4; r++) {
        int ny = ty + r * 8;
        dst[loff + (size_t)(n0 + ny) * K + k0 + tx] = tile[tx][ny];
    }
}

// ---------------- bf16 MFMA GEMM: C = act(A @ W (+bias)) -------------------
template<int EPI, bool OUTF, bool OUTB>
__global__ __launch_bounds__(256) void gemm_mfma(
    const u16* __restrict__ A, const u16* __restrict__ WT, size_t woff,
    const void* __restrict__ bias, size_t soff,
    float* __restrict__ Cf, u16* __restrict__ Cb,
    int M, int N, int K, const void* __restrict__ sniff)
{
    const int bf = detect_bf(sniff);
    __shared__ __align__(16) u16 As[128 * 32];
    __shared__ __align__(16) u16 Bs[128 * 32];
    const int tid = threadIdx.x;
    const int bm = blockIdx.y * 128, bn = blockIdx.x * 128;
    const int w = tid >> 6, lane = tid & 63;
    const int wm = (w >> 1) * 64, wn = (w & 1) * 64;
    const int lrow = lane & 15, q = lane >> 4;
    const u16* Wp = WT + woff;

    f32x4 acc[4][4];
    const f32x4 z4 = {0.f, 0.f, 0.f, 0.f};
    #pragma unroll
    for (int i = 0; i < 4; i++)
        #pragma unroll
        for (int j = 0; j < 4; j++) acc[i][j] = z4;

    for (int k0 = 0; k0 < K; k0 += 32) {
        if (k0) __syncthreads();
        #pragma unroll
        for (int c = 0; c < 2; c++) {
            int jj = tid + c * 256;            // 512 chunks of 16B per tile
            int r = jj >> 2, kc = jj & 3;
            int kg = kc ^ ((r >> 1) & 3);      // swizzled source chunk
            int ra = bm + r; if (ra >= M) ra = M - 1;
            *(s16x8*)(As + r * 32 + kc * 8) =
                *(const s16x8*)(A + (size_t)ra * K + k0 + kg * 8);
            *(s16x8*)(Bs + r * 32 + kc * 8) =
                *(const s16x8*)(Wp + (size_t)(bn + r) * K + k0 + kg * 8);
        }
        __syncthreads();
        s16x8 af[4], bfr[4];
        #pragma unroll
        for (int mt = 0; mt < 4; mt++) {
            int m_ = wm + mt * 16 + lrow;
            af[mt] = *(const s16x8*)(As + m_ * 32 + ((q ^ ((m_ >> 1) & 3)) << 3));
        }
        #pragma unroll
        for (int nt = 0; nt < 4; nt++) {
            int n_ = wn + nt * 16 + lrow;
            bfr[nt] = *(const s16x8*)(Bs + n_ * 32 + ((q ^ ((n_ >> 1) & 3)) << 3));
        }
        #pragma unroll
        for (int mt = 0; mt < 4; mt++)
            #pragma unroll
            for (int nt = 0; nt < 4; nt++)
                acc[mt][nt] = __builtin_amdgcn_mfma_f32_16x16x32_bf16(
                    af[mt], bfr[nt], acc[mt][nt], 0, 0, 0);
    }

    float bv[4] = {0.f, 0.f, 0.f, 0.f};
    if (EPI >= 1) {
        #pragma unroll
        for (int nt = 0; nt < 4; nt++)
            bv[nt] = ldw(bias, soff + (size_t)(bn + wn + nt * 16 + lrow), bf);
    }
    #pragma unroll
    for (int mt = 0; mt < 4; mt++) {
        #pragma unroll
        for (int nt = 0; nt < 4; nt++) {
            int n = bn + wn + nt * 16 + lrow;
            #pragma unroll
            for (int reg = 0; reg < 4; reg++) {
                int m = bm + wm + mt * 16 + q * 4 + reg;
                if (m < M) {
                    float v = epi_act<EPI>(acc[mt][nt][reg] + bv[nt]);
                    if (OUTF) Cf[(size_t)m * N + n] = v;
                    if (OUTB) Cb[(size_t)m * N + n] = f2b(v);
                }
            }
        }
    }
}

// ---------------- fp32 GEMM body (dt only; bf16 output) --------------------
template<int EPI>
__device__ __forceinline__ void gemm_body(
    const float* __restrict__ A,
    const void* __restrict__ Bw, size_t boff,
    const void* __restrict__ bias, size_t soff,
    u16* __restrict__ C, int N, int K, int lda, int ldb, int ldc, int bf)
{
    __shared__ float As[16][68];
    __shared__ float Bs[16][68];
    const int tid = threadIdx.x;
    const int bm = blockIdx.y * 64;
    const int bn = blockIdx.x * 64;
    const int arow = tid >> 2, acol = (tid & 3) << 2;
    const int brow = tid >> 4, bcol = (tid & 15) << 2;
    const int ty = tid >> 4, tx = tid & 15;
    float acc[4][4] = {};

    const float* aptr = A + (size_t)(bm + arow) * lda + acol;
    const size_t bidx0 = boff + (size_t)brow * ldb + bn + bcol;

    for (int k0 = 0; k0 < K; k0 += 16) {
        float4 av = *(const float4*)(aptr + k0);
        float4 bvv = ldw4(Bw, bidx0 + (size_t)k0 * ldb, bf);
        As[acol + 0][arow] = av.x;
        As[acol + 1][arow] = av.y;
        As[acol + 2][arow] = av.z;
        As[acol + 3][arow] = av.w;
        Bs[brow][bcol + 0] = bvv.x;
        Bs[brow][bcol + 1] = bvv.y;
        Bs[brow][bcol + 2] = bvv.z;
        Bs[brow][bcol + 3] = bvv.w;
        __syncthreads();
        #pragma unroll
        for (int kk = 0; kk < 16; kk++) {
            float4 a4 = *(const float4*)&As[kk][ty << 2];
            float4 b4 = *(const float4*)&Bs[kk][tx << 2];
            float ar[4] = {a4.x, a4.y, a4.z, a4.w};
            float br[4] = {b4.x, b4.y, b4.z, b4.w};
            #pragma unroll
            for (int i = 0; i < 4; i++)
                #pragma unroll
                for (int j = 0; j < 4; j++)
                    acc[i][j] = fmaf(ar[i], br[j], acc[i][j]);
        }
        __syncthreads();
    }

    float bv4[4] = {0.f, 0.f, 0.f, 0.f};
    if (EPI >= 1) {
        float4 bb = ldw4(bias, soff + (size_t)(bn + (tx << 2)), bf);
        bv4[0] = bb.x; bv4[1] = bb.y; bv4[2] = bb.z; bv4[3] = bb.w;
    }
    #pragma unroll
    for (int i = 0; i < 4; i++) {
        ushort4 o;
        o.x = f2b(epi_act<EPI>(acc[i][0] + bv4[0]));
        o.y = f2b(epi_act<EPI>(acc[i][1] + bv4[1]));
        o.z = f2b(epi_act<EPI>(acc[i][2] + bv4[2]));
        o.w = f2b(epi_act<EPI>(acc[i][3] + bv4[3]));
        *(ushort4*)(C + (size_t)(bm + (ty << 2) + i) * ldc + bn + (tx << 2)) = o;
    }
}

template<int EPI>
__global__ __launch_bounds__(256) void gemm_dual(
    const float* __restrict__ A0, const float* __restrict__ A1,
    const void* __restrict__ Bw0, size_t boff0,
    const void* __restrict__ Bw1, size_t boff1,
    const void* __restrict__ bias0, size_t sof0,
    const void* __restrict__ bias1, size_t sof1,
    u16* __restrict__ C0, u16* __restrict__ C1,
    int N, int K, int lda, int ldb, int ldc,
    const void* __restrict__ sniff)
{
    const int bf = detect_bf(sniff);
    if (blockIdx.z == 0)
        gemm_body<EPI>(A0, Bw0, boff0, bias0, sof0, C0, N, K, lda, ldb, ldc, bf);
    else
        gemm_body<EPI>(A1, Bw1, boff1, bias1, sof1, C1, N, K, lda, ldb, ldc, bf);
}

// ---------------- xproj split-K: (Mc x 1024)@(1024 x 64), K-chunk 128 ------
// A is bf16 now. grid (8, Mc/64, 2); partials P[(kc*2+dir)][Mc][64] (DTF arena).
__global__ __launch_bounds__(256) void xproj_splitk(
    const u16* __restrict__ A0, const u16* __restrict__ A1,
    const void* __restrict__ Bw0, size_t boff0,
    const void* __restrict__ Bw1, size_t boff1,
    float* __restrict__ P, int Mc, const void* __restrict__ sniff)
{
    const int bf = detect_bf(sniff);
    const int dir = blockIdx.z;
    const u16* A = dir ? A1 : A0;
    const void* Bw = dir ? Bw1 : Bw0;
    const size_t boff = dir ? boff1 : boff0;

    __shared__ float As[16][68];
    __shared__ float Bs[16][68];
    const int tid = threadIdx.x;
    const int bm = blockIdx.y * 64;
    const int kbase = blockIdx.x * 128;
    const int arow = tid >> 2, acol = (tid & 3) << 2;
    const int brow = tid >> 4, bcol = (tid & 15) << 2;
    const int ty = tid >> 4, tx = tid & 15;
    float acc[4][4] = {};

    const u16* aptr = A + (size_t)(bm + arow) * 1024 + kbase + acol;
    const size_t bidx0 = boff + (size_t)(kbase + brow) * 64 + bcol;

    for (int k0 = 0; k0 < 128; k0 += 16) {
        float4 av = ld4h(aptr, k0);
        float4 bvv = ldw4(Bw, bidx0 + (size_t)k0 * 64, bf);
        As[acol + 0][arow] = av.x;
        As[acol + 1][arow] = av.y;
        As[acol + 2][arow] = av.z;
        As[acol + 3][arow] = av.w;
        Bs[brow][bcol + 0] = bvv.x;
        Bs[brow][bcol + 1] = bvv.y;
        Bs[brow][bcol + 2] = bvv.z;
        Bs[brow][bcol + 3] = bvv.w;
        __syncthreads();
        #pragma unroll
        for (int kk = 0; kk < 16; kk++) {
            float4 a4 = *(const float4*)&As[kk][ty << 2];
            float4 b4 = *(const float4*)&Bs[kk][tx << 2];
            float ar[4] = {a4.x, a4.y, a4.z, a4.w};
            float br[4] = {b4.x, b4.y, b4.z, b4.w};
            #pragma unroll
            for (int i = 0; i < 4; i++)
                #pragma unroll
                for (int j = 0; j < 4; j++)
                    acc[i][j] = fmaf(ar[i], br[j], acc[i][j]);
        }
        __syncthreads();
    }

    float* out = P + ((size_t)(blockIdx.x * 2 + dir) * Mc + bm) * 64;
    #pragma unroll
    for (int i = 0; i < 4; i++) {
        float4 o = {acc[i][0], acc[i][1], acc[i][2], acc[i][3]};
        *(float4*)(out + (size_t)((ty << 2) + i) * 64 + (tx << 2)) = o;
    }
}

// reduce 8 split-K partials -> PRF/PRB.  grid (Mc/16, 2): dir = blockIdx.y.
__global__ __launch_bounds__(256) void xproj_reduce(
    const float* __restrict__ P, float* __restrict__ o0,
    float* __restrict__ o1, unsigned Md)
{
    const int dir = blockIdx.y;
    unsigned i = (blockIdx.x * 256 + threadIdx.x) * 4;
    const float* p = P + (size_t)dir * Md + i;
    float4 a = *(const float4*)p;
    #pragma unroll
    for (int kc = 1; kc < 8; kc++) {
        float4 bq = *(const float4*)(p + (size_t)kc * 2 * Md);
        a.x += bq.x; a.y += bq.y; a.z += bq.z; a.w += bq.w;
    }
    *(float4*)((dir ? o1 : o0) + i) = a;
}

// ---------------- patch gather (im2col) -> bf16 A ---------------------------
__global__ __launch_bounds__(256) void im2col_patch(
    const void* __restrict__ x, size_t x0, u16* __restrict__ Pb,
    const void* __restrict__ sniff)
{
    const int bf = detect_bf(sniff);
    int idx = blockIdx.x * 256 + threadIdx.x;
    int p2 = idx & 15; int r = idx >> 4;
    int p1 = r & 15;  r >>= 4;
    int w = r % 10;   r /= 10;
    int h = r % 10;   r /= 10;
    int f = r & 7;    int b = r >> 3;
    int token = f * 100 + h * 10 + w;
    size_t xb = x0 + ((size_t)(b * 32 + f * 4) * 160 + h * 16 + p1) * 160
                   + (w * 16 + p2);
    ushort4 o;
    o.x = f2b(ldw(x, xb,         bf));
    o.y = f2b(ldw(x, xb + 25600, bf));
    o.z = f2b(ldw(x, xb + 51200, bf));
    o.w = f2b(ldw(x, xb + 76800, bf));
    *(ushort4*)(Pb + (size_t)(b * 800 + token) * 1024 + ((p1 * 16 + p2) << 2)) = o;
}

// ---------------- dual depthwise conv + SiLU -> bf16 -----------------------
__global__ __launch_bounds__(256) void conv_dual(
    const float* __restrict__ xm,
    const void* __restrict__ cwF, size_t wFo,
    const void* __restrict__ cbF, size_t bFo,
    const void* __restrict__ cwB, size_t wBo,
    const void* __restrict__ cbB, size_t bBo,
    u16* __restrict__ xcf, u16* __restrict__ xcb,
    const void* __restrict__ sniff)
{
    const int bf = detect_bf(sniff);
    int idx = blockIdx.x * 256 + threadIdx.x;
    int d = idx & 1023;
    int bt = idx >> 10;
    int t = bt % 800, b = bt / 800;
    const float* base = xm + (size_t)b * 800 * 2048 + d;
    float v[7];
    #pragma unroll
    for (int j = 0; j < 7; j++) {
        int tt = t + j - 3;
        v[j] = (tt >= 0 && tt < 800) ? base[(size_t)tt * 2048] : 0.f;
    }
    float4 wf = ldw4(cwF, wFo + (size_t)d * 4, bf);
    float4 wb = ldw4(cwB, wBo + (size_t)d * 4, bf);
    float f = ldw(cbF, bFo + d, bf) + wf.x * v[0] + wf.y * v[1]
                                    + wf.z * v[2] + wf.w * v[3];
    float g = ldw(cbB, bBo + d, bf) + wb.x * v[6] + wb.y * v[5]
                                    + wb.z * v[4] + wb.w * v[3];
    xcf[(size_t)bt * 1024 + d] = f2b(f / (1.f + __expf(-f)));
    xcb[(size_t)bt * 1024 + d] = f2b(g / (1.f + __expf(-g)));
}

// ---------------- segmented selective scan (round 16: bf16 dt/u/y) ---------
// scratch = u16 planes in the dead XZ x-half: u16 index i ->
// XZ_u16[(i>>11)*4096 + (i&2047)] (row = 2048 u16 of x-half, stride 4096).
__device__ __forceinline__ u16& scrh(u16* s, unsigned i) {
    return s[(size_t)(i >> 11) * 4096 + (i & 2047)];
}

// q^(1..16) with 15 muls, depth <= 4 (epilogue only)
__device__ __forceinline__ void pow16(float q, float* e) {
    float q2 = q * q, q4 = q2 * q2, q8 = q4 * q4;
    e[0] = q;        e[1] = q2;       e[2] = q2 * q;   e[3] = q4;
    e[4] = q4 * q;   e[5] = q4 * q2;  e[6] = e[5] * q; e[7] = q8;
    e[8] = q8 * q;   e[9] = q8 * q2;  e[10] = e[9] * q; e[11] = q8 * q4;
    e[12] = e[11] * q; e[13] = e[11] * q2; e[14] = e[13] * q; e[15] = q8 * q8;
}

// PASS=1: per-segment transfer (E via exp2(ac*sum dt), h_end from 0) -> scratch.
// PASS=3: full scan with h_in from scratch; y = c + u*D in place over u (bf16).
template<int DIR, int PASS, bool POW>
__device__ __forceinline__ void scan_seg_body(
    const u16* u, const u16* dt, const float* __restrict__ pr,
    const void* __restrict__ Al, size_t ao,
    const void* __restrict__ Dp, size_t dofs,
    u16* y, u16* scr, unsigned NSd, int b, int seg, int bf,
    float* lds, float* acl)
{
    const int tid = threadIdx.x;
    const int d = blockIdx.x * 256 + tid;
    const long rb = (long)b * 800;
    constexpr int S = DIR ? -1 : 1;
    const int t0 = DIR ? 799 - seg * SEGLEN : seg * SEGLEN;

    // stage this segment's B/C rows into LDS: lds[tau][32] (tau in [0,40))
    for (int i = tid; i < SEGLEN * 8; i += 256) {
        int tr = i >> 3, c4 = (i & 7) * 4;
        long tt = (long)t0 + (long)(S * tr);
        *(float4*)&lds[tr * 32 + c4] =
            *(const float4*)&pr[(rb + tt) * 64 + 32 + c4];
    }

    // per-lane constants: POW keeps only ac0; generic parks ac[16] in LDS
    float ac0;
    if (POW) {
        ac0 = -__expf(ldw(Al, ao + (size_t)d * 16, bf)) * 1.44269504f;
    } else {
        #pragma unroll
        for (int n = 0; n < 16; n++)
            acl[tid * 16 + n] =
                -__expf(ldw(Al, ao + (size_t)d * 16 + n, bf)) * 1.44269504f;
        ac0 = acl[tid * 16];
    }
    __syncthreads();
    const float Dv = (PASS == 3) ? ldw(Dp, dofs + d, bf) : 0.f;

    const unsigned sidx = ((unsigned)((b * 2 + DIR) * NSEG + seg) << 10) + d;
    float h[16];
    if (PASS == 3) {
        #pragma unroll
        for (int n = 0; n < 16; n++) h[n] = b2f(scrh(scr, (16 + n) * NSd + sidx));
    } else {
        #pragma unroll
        for (int n = 0; n < 16; n++) h[n] = 0.f;
    }
    float dtsum = 0.f;

    const u16* pdt = dt + (rb + t0) * 1024 + d;
    const u16* pu  = u  + (rb + t0) * 1024 + d;
    u16*       py  = y  + (rb + t0) * 1024 + d;

    float dA[8], uA[8], dB[8], uB_[8];
    #pragma unroll
    for (int j = 0; j < 8; j++) {
        dA[j] = b2f(pdt[S * j * 1024]); uA[j] = b2f(pu[S * j * 1024]);
    }
    pdt += S * 8192; pu += S * 8192;

    for (int it = 0; it < SEGLEN / 8; it++) {
        // prefetch next 8 steps (last iteration over-reads 8 rows: discarded,
        // and the addresses stay inside the same (oversized) arenas)
        #pragma unroll
        for (int j = 0; j < 8; j++) {
            dB[j] = b2f(pdt[S * j * 1024]); uB_[j] = b2f(pu[S * j * 1024]);
        }
        pdt += S * 8192; pu += S * 8192;

        #pragma unroll
        for (int j = 0; j < 8; j++) {
            const float dtv = dA[j], uv = uA[j];
            const float du = dtv * uv;
            if (PASS == 1) dtsum += dtv;
            const float* bcp = lds + (it * 8 + j) * 32;
            float s0 = 0.f, s1 = 0.f;
            if (POW) {
                float qq = EXP2F(dtv * ac0);
                float q2 = qq * qq;
                float e0 = qq, e1 = q2, e2 = q2 * qq, e3 = q2 * q2;
                const float q4 = e3;
                #pragma unroll
                for (int c = 0; c < 4; c++) {
                    float4 bq = *(const float4*)&bcp[c * 4];
                    h[c*4+0] = e0 * h[c*4+0] + du * bq.x;
                    h[c*4+1] = e1 * h[c*4+1] + du * bq.y;
                    h[c*4+2] = e2 * h[c*4+2] + du * bq.z;
                    h[c*4+3] = e3 * h[c*4+3] + du * bq.w;
                    if (PASS == 3) {
                        float4 cq = *(const float4*)&bcp[16 + c * 4];
                        s0 = fmaf(h[c*4+0], cq.x, fmaf(h[c*4+1], cq.y, s0));
                        s1 = fmaf(h[c*4+2], cq.z, fmaf(h[c*4+3], cq.w, s1));
                    }
                    if (c < 3) { e0 *= q4; e1 *= q4; e2 *= q4; e3 *= q4; }
                }
            } else {
                #pragma unroll
                for (int c = 0; c < 4; c++) {
                    float4 bq = *(const float4*)&bcp[c * 4];
                    float e0 = EXP2F(dtv * acl[tid * 16 + c*4+0]);
                    float e1 = EXP2F(dtv * acl[tid * 16 + c*4+1]);
                    float e2 = EXP2F(dtv * acl[tid * 16 + c*4+2]);
                    float e3 = EXP2F(dtv * acl[tid * 16 + c*4+3]);
                    h[c*4+0] = e0 * h[c*4+0] + du * bq.x;
                    h[c*4+1] = e1 * h[c*4+1] + du * bq.y;
                    h[c*4+2] = e2 * h[c*4+2] + du * bq.z;
                    h[c*4+3] = e3 * h[c*4+3] + du * bq.w;
                    if (PASS == 3) {
                        float4 cq = *(const float4*)&bcp[16 + c * 4];
                        s0 = fmaf(h[c*4+0], cq.x, fmaf(h[c*4+1], cq.y, s0));
                        s1 = fmaf(h[c*4+2], cq.z, fmaf(h[c*4+3], cq.w, s1));
                    }
                }
            }
            if (PASS == 3) py[S * j * 1024] = f2b(fmaf(uv, Dv, s0 + s1));
        }
        if (PASS == 3) py += S * 8192;
        #pragma unroll
        for (int j = 0; j < 8; j++) { dA[j] = dB[j]; uA[j] = uB_[j]; }
    }

    if (PASS == 1) {
        float E[16];
        if (POW) {
            pow16(EXP2F(dtsum * ac0), E);
        } else {
            #pragma unroll
            for (int n = 0; n < 16; n++) E[n] = EXP2F(dtsum * acl[tid * 16 + n]);
        }
        #pragma unroll
        for (int n = 0; n < 16; n++) {
            scrh(scr, n * NSd + sidx)        = f2b(E[n]);
            scrh(scr, (16 + n) * NSd + sidx) = f2b(h[n]);
        }
    }
}

template<int PASS>
__global__ __launch_bounds__(256, 4) void ssm_seg(
    const u16* uF, const u16* dtF, const float* __restrict__ pF,
    const u16* uB, const u16* dtB, const float* __restrict__ pB,
    const void* __restrict__ AlF, const void* __restrict__ AlB, size_t ao,
    const void* __restrict__ DF,  const void* __restrict__ DB,  size_t dofs,
    u16* yF, u16* yB, u16* scr, unsigned NSd,
    const void* __restrict__ sniff)
{
    __shared__ float lds[SEGLEN * 32];
    __shared__ float acl[256 * 16];
    const int bf = detect_bf(sniff);
    const int b = blockIdx.y;
    const int z = blockIdx.z;
    const int dir = z >= NSEG ? 1 : 0;
    const int seg = dir ? z - NSEG : z;
    const int d = blockIdx.x * 256 + threadIdx.x;

    // detect A-structure: A_log[d][n] == A_log[d][0] + log(n+1)  (per wave)
    const void* Al = dir ? AlB : AlF;
    float m0 = __expf(ldw(Al, ao + (size_t)d * 16 + 0, bf));
    bool okb = true;
    #pragma unroll
    for (int n = 1; n < 16; n++) {
        float mn = __expf(ldw(Al, ao + (size_t)d * 16 + n, bf));
        okb &= fabsf(mn - (n + 1) * m0) <= 1e-3f * (n + 1) * m0;
    }
    const bool ok = __all(okb) != 0;

    if (dir == 0) {
        if (ok) scan_seg_body<0, PASS, true >(uF, dtF, pF, AlF, ao, DF, dofs,
                                              yF, scr, NSd, b, seg, bf, lds, acl);
        else    scan_seg_body<0, PASS, false>(uF, dtF, pF, AlF, ao, DF, dofs,
                                              yF, scr, NSd, b, seg, bf, lds, acl);
    } else {
        if (ok) scan_seg_body<1, PASS, true >(uB, dtB, pB, AlB, ao, DB, dofs,
                                              yB, scr, NSd, b, seg, bf, lds, acl);
        else    scan_seg_body<1, PASS, false>(uB, dtB, pB, AlB, ao, DB, dofs,
                                              yB, scr, NSd, b, seg, bf, lds, acl);
    }
}

// pass 2: sequential cross-segment combine; rewrites h_end slot with h_in.
// h carried in fp32 internally; scratch slots are bf16.
__global__ __launch_bounds__(256) void ssm_comb(u16* scr, unsigned NSd)
{
    int idx = blockIdx.x * 256 + threadIdx.x;   // (bdir*16 + n)*1024 + d
    int d = idx & 1023;
    int n = (idx >> 10) & 15;
    int bdir = idx >> 14;
    float h = 0.f;
    for (int s = 0; s < NSEG; s++) {
        unsigned sidx = ((unsigned)(bdir * NSEG + s) << 10) + d;
        float Ev = b2f(scrh(scr, n * NSd + sidx));
        float He = b2f(scrh(scr, (16 + n) * NSd + sidx));
        scrh(scr, (16 + n) * NSd + sidx) = f2b(h);
        h = Ev * h + He;
    }
}

// ---------------- (yF + yB) * silu(z) -> bf16 (out_proj A) -----------------
// yF/yB now bf16.
__global__ __launch_bounds__(256) void addcvt(
    const u16* __restrict__ a, const u16* __restrict__ b,
    const float* __restrict__ z, u16* __restrict__ o)
{
    int i = (blockIdx.x * 256 + threadIdx.x) * 4;
    int t = i >> 10, d = i & 1023;
    float4 va = ld4h(a, i);
    float4 vb = ld4h(b, i);
    float4 vz = *(const float4*)(z + (size_t)t * 2048 + 1024 + d);
    float s0 = vz.x / (1.f + __expf(-vz.x));
    float s1 = vz.y / (1.f + __expf(-vz.y));
    float s2 = vz.z / (1.f + __expf(-vz.z));
    float s3 = vz.w / (1.f + __expf(-vz.w));
    ushort4 r;
    r.x = f2b((va.x + vb.x) * s0); r.y = f2b((va.y + vb.y) * s1);
    r.z = f2b((va.z + vb.z) * s2); r.w = f2b((va.w + vb.w) * s3);
    *(ushort4*)(o + i) = r;
}

// ---------------- LayerNorm + residual -> XT fp32 + XTb bf16 (+fp32 out) ---
__global__ __launch_bounds__(256) void ln_residual(
    const float* __restrict__ Y, const void* __restrict__ g, size_t go,
    const void* __restrict__ bb, size_t bo,
    float* __restrict__ XT, u16* __restrict__ XTb, float* __restrict__ out,
    const void* __restrict__ sniff)
{
    const int bf = detect_bf(sniff);
    int wv = threadIdx.x >> 6, lane = threadIdx.x & 63;
    int token = blockIdx.x * 4 + wv;
    const float* y = Y + (size_t)token * 512;
    float v[8], s = 0.f, s2 = 0.f;
    #pragma unroll
    for (int j = 0; j < 8; j++) {
        v[j] = y[lane + j * 64];
        s += v[j]; s2 += v[j] * v[j];
    }
    #pragma unroll
    for (int off = 32; off >= 1; off >>= 1) {
        s  += __shfl_xor(s,  off, 64);
        s2 += __shfl_xor(s2, off, 64);
    }
    float mean = s * (1.f / 512.f);
    float var  = s2 * (1.f / 512.f) - mean * mean;
    float rs = rsqrtf(var + 1e-5f);
    float* xt = XT + (size_t)token * 512;
    #pragma unroll
    for (int j = 0; j < 8; j++) {
        int c = lane + j * 64;
        float val = (v[j] - mean) * rs * ldw(g, go + c, bf)
                  + ldw(bb, bo + c, bf) + xt[c];
        xt[c] = val;
        XTb[(size_t)token * 512 + c] = f2b(val);
        if (out) out[(size_t)token * 512 + c] = val;
    }
}

// ---------------------------------------------------------------------------
extern "C" void kernel_launch(void* const* d_in, const int* in_sizes, int n_in,
                              void* d_out, int out_size, void* d_ws, size_t ws_size,
                              hipStream_t stream)
{
    (void)in_sizes; (void)n_in; (void)out_size;
    const void* X      = d_in[0];
    const void* patchW = d_in[1];
    const void* patchB = d_in[2];
    const void* inW    = d_in[3];
    const void* convW  = d_in[4];
    const void* convBi = d_in[5];
    const void* xprojW = d_in[6];
    const void* dtW    = d_in[7];
    const void* dtBias = d_in[8];
    const void* Alog   = d_in[9];
    const void* Dsk    = d_in[10];
    const void* convWb = d_in[11];
    const void* convBb = d_in[12];
    const void* xprojWb= d_in[13];
    const void* dtWb   = d_in[14];
    const void* dtBiasb= d_in[15];
    const void* Alogb  = d_in[16];
    const void* Dskb   = d_in[17];
    const void* outW   = d_in[18];
    const void* ln1g   = d_in[19];
    const void* ln1b   = d_in[20];
    const void* fc1W   = d_in[21];
    const void* fc1B   = d_in[22];
    const void* fc2W   = d_in[23];
    const void* fc2B   = d_in[24];
    const void* ln2g   = d_in[25];
    const void* ln2b   = d_in[26];
    const void* SN     = patchW;            // dtype sniff target

    // bf16 weight arena (u16 offsets)
    const size_t IN_OFF  = 524288;          // after patchWT
    const size_t OUT_OFF = 8912896;
    const size_t FC1_OFF = 13107200;
    const size_t FC2_OFF = 17301504;
    const size_t WB_FLOATS = 10747904;      // 21495808 u16 / 2

    // chunking: bytes = (WB + Mc*8064 + pad)*4
    int nc = 1;
    auto need = [&](int Mc) {
        return (WB_FLOATS + (size_t)Mc * 8064 + 16384) * 4;
    };
    if (need(6400) > ws_size) nc = 2;
    if (need(3200) > ws_size) nc = 4;
    const int bc = 8 / nc;
    const int Mc = bc * 800;
    const int GY = Mc / 64;                 // fp32-GEMM grid
    const int GYM = (Mc + 127) / 128;       // MFMA grid
    const unsigned NSd = (unsigned)bc * 2 * NSEG * 1024;   // scratch streams

    u16* WB = (u16*)d_ws;
    float* cur = (float*)d_ws + WB_FLOATS;
    float* XT  = cur;              cur += (size_t)Mc * 512;
    u16*  XTb  = (u16*)cur;        cur += (size_t)Mc * 256;
    float* XZ  = cur;              cur += (size_t)Mc * 2048;
    u16*  XCF  = (u16*)cur;        cur += (size_t)Mc * 1024;   // bf16 u/y (arena fp32-sized)
    u16*  XCB  = (u16*)cur;        cur += (size_t)Mc * 1024;
    float* PRF = cur;              cur += (size_t)Mc * 64;
    float* PRB = cur;              cur += (size_t)Mc * 64;
    float* DTP = cur;              cur += (size_t)Mc * 1024;   // splitk partials (fp32)
    u16*  DTF  = (u16*)DTP;                                    // bf16 dt after reduce+GEMM
    u16*  DTB  = (u16*)cur;        cur += (size_t)Mc * 1024;
    u16*  M1b  = (u16*)cur;        cur += (size_t)Mc * 512;
    u16*  YSb  = (u16*)cur;        cur += (size_t)Mc * 512;
    u16*  PATCHb = (u16*)XCF;               // alias (dead before conv)
    float* YO  = XZ;                        // alias (XZ dead post-scan)
    float* M2  = XZ + (size_t)Mc * 512;     // alias, disjoint from YO

    // ---- one-time weight transpose-convert to bf16 [N][K] -----------------
    transp_cvt<<<dim3(16, 32, 1), dim3(32, 8), 0, stream>>>(patchW, WB, 1024, 512, SN);
    transp_cvt<<<dim3(64, 16, 8), dim3(32, 8), 0, stream>>>(inW,  WB + IN_OFF, 512, 2048, SN);
    transp_cvt<<<dim3(16, 32, 8), dim3(32, 8), 0, stream>>>(outW, WB + OUT_OFF, 1024, 512, SN);
    transp_cvt<<<dim3(32, 16, 8), dim3(32, 8), 0, stream>>>(fc1W, WB + FC1_OFF, 512, 1024, SN);
    transp_cvt<<<dim3(16, 32, 8), dim3(32, 8), 0, stream>>>(fc2W, WB + FC2_OFF, 1024, 512, SN);

    for (int c = 0; c < nc; c++) {
        const size_t x0 = (size_t)c * bc * 819200;

        im2col_patch<<<Mc, 256, 0, stream>>>(X, x0, PATCHb, SN);
        // patch embed: (Mc x 1024) @ (1024 x 512) + bias -> XT fp32 + XTb bf16
        gemm_mfma<1, true, true><<<dim3(4, GYM), 256, 0, stream>>>(
            PATCHb, WB, 0, patchB, 0, XT, XTb, Mc, 512, 1024, SN);

        for (int l = 0; l < 8; l++) {
            // in_proj: (Mc x 512) @ (512 x 2048) -> XZ fp32
            gemm_mfma<0, true, false><<<dim3(16, GYM), 256, 0, stream>>>(
                XTb, WB, IN_OFF + (size_t)l * 1048576, nullptr, 0,
                XZ, nullptr, Mc, 2048, 512, SN);
            // depthwise conv both dirs + SiLU -> bf16
            conv_dual<<<Mc * 4, 256, 0, stream>>>(
                XZ, convW, (size_t)l * 4096, convBi, (size_t)l * 1024,
                convWb, (size_t)l * 4096, convBb, (size_t)l * 1024,
                XCF, XCB, SN);
            // x-proj both dirs, split-K 8 (bf16 A, fp32 math): partials in DTP
            xproj_splitk<<<dim3(8, GY, 2), 256, 0, stream>>>(
                XCF, XCB, xprojW, (size_t)l * 65536, xprojWb, (size_t)l * 65536,
                DTP, Mc, SN);
            xproj_reduce<<<dim3(Mc / 16, 2), 256, 0, stream>>>(
                DTP, PRF, PRB, (unsigned)Mc * 64);
            // dt both dirs (fp32 math): softplus(... ) -> bf16 DTF/DTB
            gemm_dual<2><<<dim3(16, GY, 2), 256, 0, stream>>>(
                PRF, PRB, dtW, (size_t)l * 32768, dtWb, (size_t)l * 32768,
                dtBias, (size_t)l * 1024, dtBiasb, (size_t)l * 1024,
                DTF, DTB, 1024, 32, 64, 1024, 1024, SN);
            // segmented selective scan: pass1 (transfer), pass2 (combine),
            // pass3 (scan; in-place bf16 y = c + u*D over u). scratch = XZ x-half.
            ssm_seg<1><<<dim3(4, bc, 2 * NSEG), 256, 0, stream>>>(
                XCF, DTF, PRF, XCB, DTB, PRB,
                Alog, Alogb, (size_t)l * 16384,
                Dsk, Dskb, (size_t)l * 1024,
                XCF, XCB, (u16*)XZ, NSd, SN);
            ssm_comb<<<bc * 128, 256, 0, stream>>>((u16*)XZ, NSd);
            ssm_seg<3><<<dim3(4, bc, 2 * NSEG), 256, 0, stream>>>(
                XCF, DTF, PRF, XCB, DTB, PRB,
                Alog, Alogb, (size_t)l * 16384,
                Dsk, Dskb, (size_t)l * 1024,
                XCF, XCB, (u16*)XZ, NSd, SN);
            // (yF + yB) * silu(z) -> bf16
            addcvt<<<Mc, 256, 0, stream>>>(XCF, XCB, XZ, YSb);
            // out_proj: (Mc x 1024) @ (1024 x 512) -> YO fp32
            gemm_mfma<0, true, false><<<dim3(4, GYM), 256, 0, stream>>>(
                YSb, WB, OUT_OFF + (size_t)l * 524288, nullptr, 0,
                YO, nullptr, Mc, 512, 1024, SN);
            ln_residual<<<Mc / 4, 256, 0, stream>>>(
                YO, ln1g, (size_t)l * 512, ln1b, (size_t)l * 512,
                XT, XTb, nullptr, SN);
            // fc1: (Mc x 512) @ (512 x 1024) + bias, gelu -> M1b bf16
            gemm_mfma<3, false, true><<<dim3(8, GYM), 256, 0, stream>>>(
                XTb, WB, FC1_OFF + (size_t)l * 524288, fc1B, (size_t)l * 1024,
                nullptr, M1b, Mc, 1024, 512, SN);
            // fc2: (Mc x 1024) @ (1024 x 512) + bias -> M2 fp32
            gemm_mfma<1, true, false><<<dim3(4, GYM), 256, 0, stream>>>(
                M1b, WB, FC2_OFF + (size_t)l * 524288, fc2B, (size_t)l * 512,
                M2, nullptr, Mc, 512, 1024, SN);
            ln_residual<<<Mc / 4, 256, 0, stream>>>(
                M2, ln2g, (size_t)l * 512, ln2b, (size_t)l * 512,
                XT, XTb,
                (float*)d_out + (size_t)l * 3276800 + (size_t)c * Mc * 512, SN);
        }
    }
}